// Round 10
// baseline (214.097 us; speedup 1.0000x reference)
//
#include <hip/hip_runtime.h>
#include <math.h>

#define D_MODEL 1024
#define NUM_HEADS 16
#define D_HEAD 64
#define SEQ 2048
#define BATCH 2

typedef __attribute__((ext_vector_type(8))) short short8;
typedef __attribute__((ext_vector_type(4))) short short4v;
typedef __attribute__((ext_vector_type(4))) float float4v;

__device__ __forceinline__ short f2bf(float f) {
    unsigned u = __float_as_uint(f);
    u += 0x7FFFu + ((u >> 16) & 1u);
    return (short)(u >> 16);
}

// async global->LDS, 16B/lane; LDS dest = wave-uniform base + lane*16.
#define GLOAD_LDS16(g, l)                                                     \
    __builtin_amdgcn_global_load_lds(                                         \
        (const __attribute__((address_space(1))) unsigned int*)(g),           \
        (__attribute__((address_space(3))) unsigned int*)(l), 16, 0, 0)

// ---------------------------------------------------------------------------
// Kernel 0: fp32 -> bf16 conversion + RoPE cos/sin table (all libm here;
// NEVER in hot MFMA kernels — R8: sincosf codegen = scratch-spill GBs).
// ---------------------------------------------------------------------------
__global__ __launch_bounds__(256) void cvt_bf16_kernel(
    const float* __restrict__ x,  const float* __restrict__ wq,
    const float* __restrict__ wk, const float* __restrict__ wv,
    const float* __restrict__ wo, const int* __restrict__ pos,
    short* __restrict__ xb,  short* __restrict__ wqb,
    short* __restrict__ wkb, short* __restrict__ wvb,
    short* __restrict__ wob,
    float* __restrict__ costab, float* __restrict__ sintab)
{
    const int a = blockIdx.y;
    if (a == 5) {                          // RoPE table: idx = s*32 + fi
        const int idx = blockIdx.x * 256 + threadIdx.x;
        if (idx < SEQ * 32) {
            const int s = idx >> 5, fi = idx & 31;
            const float p = (float)pos[s];
            const float inv_freq = exp2f((float)fi * -0.4152410118609203f);
            float sn, cs;
            sincosf(p * inv_freq, &sn, &cs);
            costab[idx] = cs;
            sintab[idx] = sn;
        }
        return;
    }
    const float* src = (a == 0) ? x : (a == 1) ? wq : (a == 2) ? wk : (a == 3) ? wv : wo;
    short* dst = (a == 0) ? xb : (a == 1) ? wqb : (a == 2) ? wkb : (a == 3) ? wvb : wob;
    const int n = (a == 0) ? (BATCH * SEQ * D_MODEL) : (D_MODEL * D_MODEL);
    const int i = (blockIdx.x * 256 + threadIdx.x) * 8;
    if (i >= n) return;
    const float4 v0 = *(const float4*)(src + i);
    const float4 v1 = *(const float4*)(src + i + 4);
    short8 r;
    r[0] = f2bf(v0.x); r[1] = f2bf(v0.y); r[2] = f2bf(v0.z); r[3] = f2bf(v0.w);
    r[4] = f2bf(v1.x); r[5] = f2bf(v1.y); r[6] = f2bf(v1.z); r[7] = f2bf(v1.w);
    *(short8*)(dst + i) = r;
}

// ---------------------------------------------------------------------------
// m97-structure bf16 MFMA GEMM core: global_load_lds width-16 staging,
// single buffer, 2 barriers per BK=32 step. R3/R4's condemnation of this
// path was confounded by sincosf scratch traffic (R8); retrying clean.
// ---------------------------------------------------------------------------
__device__ __forceinline__ void gemm_core_lds(
    const short* __restrict__ a, const short* __restrict__ b,
    short* lA, short* lB, int m0, int n0, float4v acc[4][4])
{
    const int tid = threadIdx.x;
    const int lane = tid & 63;
    const int l15 = lane & 15, quad = lane >> 4;
    const int wave = tid >> 6;
    const int mw = (wave & 1) * 64, nw = (wave >> 1) * 64;
    const int srow = tid >> 2;            // 0..63
    const int scol = (tid & 3) * 8;       // 0,8,16,24

    const short* ag = a + (size_t)(m0 + srow) * D_MODEL + scol;
    const short* bg = b + (size_t)(n0 + srow) * D_MODEL + scol;
    short* lAd = lA + tid * 8;            // wave-uniform base + lane*16B
    short* lBd = lB + tid * 8;

    for (int k0 = 0; k0 < D_MODEL; k0 += 32) {
        __syncthreads();                  // prior iter's ds_reads done
        GLOAD_LDS16(ag + k0, lAd);
        GLOAD_LDS16(ag + k0 + (size_t)64 * D_MODEL, lAd + 2048);
        GLOAD_LDS16(bg + k0, lBd);
        GLOAD_LDS16(bg + k0 + (size_t)64 * D_MODEL, lBd + 2048);
        __syncthreads();                  // DMA drained; tile visible

        short8 af[4], bf[4];
        #pragma unroll
        for (int i = 0; i < 4; i++)
            af[i] = *(const short8*)&lA[(mw + i * 16 + l15) * 32 + quad * 8];
        #pragma unroll
        for (int i = 0; i < 4; i++)
            bf[i] = *(const short8*)&lB[(nw + i * 16 + l15) * 32 + quad * 8];
        #pragma unroll
        for (int mi = 0; mi < 4; mi++)
            #pragma unroll
            for (int ni = 0; ni < 4; ni++)
                acc[mi][ni] = __builtin_amdgcn_mfma_f32_16x16x32_bf16(
                    af[mi], bf[ni], acc[mi][ni], 0, 0, 0);
    }
}

// ---------------------------------------------------------------------------
// Kernel 1: fused QKV projection. z = bid>>8 (0=Q rope, 1=K rope, 2=V^T).
// Table-RoPE epilogue, LDS-staged coalesced stores. No transcendentals.
// ---------------------------------------------------------------------------
__global__ __launch_bounds__(256) void qkv_mfma_kernel(
    const short* __restrict__ xb, const short* __restrict__ wqb,
    const short* __restrict__ wkb, const short* __restrict__ wvb,
    const float* __restrict__ costab, const float* __restrict__ sintab,
    short* __restrict__ Qb, short* __restrict__ Kb, short* __restrict__ Vt)
{
    __shared__ __align__(16) short smem[128 * 136];   // gemm uses first 16 KB

    const int z = blockIdx.x >> 8;
    const int bid = blockIdx.x & 255;
    const int m0 = (bid & 31) * 128;
    const int n0 = (bid >> 5) * 128;
    const short* w = (z == 0) ? wqb : (z == 1) ? wkb : wvb;

    float4v acc[4][4];
    #pragma unroll
    for (int i = 0; i < 4; i++)
        #pragma unroll
        for (int j = 0; j < 4; j++)
            acc[i][j] = (float4v){0.f, 0.f, 0.f, 0.f};

    gemm_core_lds(xb, w, smem, smem + 4096, m0, n0, acc);

    const int tid = threadIdx.x;
    const int lane = tid & 63;
    const int l15 = lane & 15, quad = lane >> 4;
    const int wave = tid >> 6;
    const int mw = (wave & 1) * 64, nw = (wave >> 1) * 64;
    const int s_base = m0 & (SEQ - 1);
    const int bb = m0 >> 11;

    __syncthreads();

    if (z == 2) {
        #pragma unroll
        for (int ni = 0; ni < 4; ni++) {
            #pragma unroll
            for (int mi = 0; mi < 4; mi++) {
                #pragma unroll
                for (int r = 0; r < 4; r++)
                    smem[(nw + ni * 16 + l15) * 136 + mw + mi * 16 + quad * 4 + r] =
                        f2bf(acc[mi][ni][r]);
            }
        }
        __syncthreads();
        #pragma unroll
        for (int it = 0; it < 8; it++) {
            const int nloc = it * 16 + (tid >> 4);
            const int mloc = (tid & 15) * 8;
            const short8 val = *(const short8*)&smem[nloc * 136 + mloc];
            const int n = n0 + nloc;
            const int h = n >> 6, d = n & 63;
            *(short8*)(Vt + ((size_t)(bb * NUM_HEADS + h) * D_HEAD + d) * SEQ +
                       s_base + mloc) = val;
        }
    } else {
        short* dst = (z == 0) ? Qb : Kb;
        const float qs = (z == 0) ? 0.125f : 1.0f;
        #pragma unroll
        for (int ni = 0; ni < 4; ni++) {
            const int n = n0 + nw + ni * 16 + l15;
            const int d = n & 63;
            const int fi = d >> 1;
            #pragma unroll
            for (int mi = 0; mi < 4; mi++) {
                #pragma unroll
                for (int r = 0; r < 4; r++) {
                    const int mloc = mw + mi * 16 + quad * 4 + r;
                    const int ti = ((s_base + mloc) << 5) + fi;
                    const float cs = costab[ti];
                    const float sn = sintab[ti];
                    const float val = acc[mi][ni][r];
                    const float partner = __shfl_xor(val, 1, 64);
                    const float res = (l15 & 1) ? fmaf(partner, sn, val * cs)
                                                : fmaf(val, cs, -partner * sn);
                    smem[mloc * 136 + nw + ni * 16 + l15] = f2bf(res * qs);
                }
            }
        }
        __syncthreads();
        #pragma unroll
        for (int it = 0; it < 8; it++) {
            const int ri = it * 32 + (tid >> 3);
            const int mloc = ri & 127;
            const int hh = ri >> 7;
            const int nloc = hh * 64 + (tid & 7) * 8;
            const short8 val = *(const short8*)&smem[mloc * 136 + nloc];
            const int n = n0 + nloc;
            const int h = n >> 6, d = n & 63;
            *(short8*)(dst + ((size_t)(bb * NUM_HEADS + h) * SEQ + s_base + mloc) *
                       D_HEAD + d) = val;
        }
    }
}

// ---------------------------------------------------------------------------
// Kernel 2: causal flash attention (R9 S^T-restructure — unchanged control).
// ---------------------------------------------------------------------------
__global__ __launch_bounds__(256) void attn_mfma_kernel(
    const short* __restrict__ Qb, const short* __restrict__ Kb,
    const short* __restrict__ Vt, short* __restrict__ Ab)
{
    __shared__ __align__(16) short lK[64 * 72];
    __shared__ __align__(16) short lV[64 * 72];
    __shared__ __align__(16) short lP[4][16 * 72];

    const int tid = threadIdx.x;
    const int lane = tid & 63;
    const int wave = tid >> 6;
    const int l15 = lane & 15;
    const int quad = lane >> 4;

    const int bh = blockIdx.x & (BATCH * NUM_HEADS - 1);
    const int qt = (SEQ / 64 - 1) - (blockIdx.x >> 5);   // longest first
    const int q0w = qt * 64 + wave * 16;
    const int qcmp = q0w + l15;

    const short* Kg = Kb + (size_t)bh * SEQ * D_HEAD;
    const short* Vg = Vt + (size_t)bh * D_HEAD * SEQ;

    const short* Qrow = Qb + ((size_t)bh * SEQ + q0w + l15) * D_HEAD;
    const short8 qf0 = *(const short8*)(Qrow + quad * 8);
    const short8 qf1 = *(const short8*)(Qrow + 32 + quad * 8);

    float4v o0 = {0.f, 0.f, 0.f, 0.f}, o1 = o0, o2 = o0, o3 = o0;
    float lp = 0.f;

    const int nt = qt + 1;                 // 64-key tiles
    const int srow = tid >> 2;             // 0..63
    const int sch = (tid & 3) * 8;         // 0,8,16,24 shorts

    short8 k0 = *(const short8*)(Kg + (size_t)srow * D_HEAD + sch);
    short8 k1 = *(const short8*)(Kg + (size_t)srow * D_HEAD + sch + 32);
    short8 v0 = *(const short8*)(Vg + (size_t)srow * SEQ + sch);
    short8 v1 = *(const short8*)(Vg + (size_t)srow * SEQ + sch + 32);

    for (int t = 0; t < nt; t++) {
        const int kt0 = t * 64;
        __syncthreads();
        *(short8*)&lK[srow * 72 + sch]      = k0;
        *(short8*)&lK[srow * 72 + sch + 32] = k1;
        *(short8*)&lV[srow * 72 + sch]      = v0;
        *(short8*)&lV[srow * 72 + sch + 32] = v1;
        __syncthreads();
        if (t + 1 < nt) {
            k0 = *(const short8*)(Kg + (size_t)(kt0 + 64 + srow) * D_HEAD + sch);
            k1 = *(const short8*)(Kg + (size_t)(kt0 + 64 + srow) * D_HEAD + sch + 32);
            v0 = *(const short8*)(Vg + (size_t)srow * SEQ + kt0 + 64 + sch);
            v1 = *(const short8*)(Vg + (size_t)srow * SEQ + kt0 + 64 + sch + 32);
        }

        short* Pw = lP[wave];
        #pragma unroll
        for (int g = 0; g < 4; g++) {
            float4v s = {0.f, 0.f, 0.f, 0.f};
            const short8 ka = *(const short8*)&lK[(g * 16 + l15) * 72 + quad * 8];
            s = __builtin_amdgcn_mfma_f32_16x16x32_bf16(ka, qf0, s, 0, 0, 0);
            const short8 kb = *(const short8*)&lK[(g * 16 + l15) * 72 + 32 + quad * 8];
            s = __builtin_amdgcn_mfma_f32_16x16x32_bf16(kb, qf1, s, 0, 0, 0);

            const int kbase = kt0 + g * 16 + quad * 4;
            short4v pk;
            #pragma unroll
            for (int r = 0; r < 4; r++) {
                const float e = (kbase + r <= qcmp) ? __expf(s[r]) : 0.f;
                lp += e;
                pk[r] = f2bf(e);
            }
            *(short4v*)&Pw[l15 * 72 + g * 16 + quad * 4] = pk;
        }

        const short8 pa0 = *(const short8*)&lP[wave][l15 * 72 + quad * 8];
        const short8 pa1 = *(const short8*)&lP[wave][l15 * 72 + 32 + quad * 8];

        {
            const short8 va = *(const short8*)&lV[(0 * 16 + l15) * 72 + quad * 8];
            const short8 vb = *(const short8*)&lV[(0 * 16 + l15) * 72 + 32 + quad * 8];
            o0 = __builtin_amdgcn_mfma_f32_16x16x32_bf16(pa0, va, o0, 0, 0, 0);
            o0 = __builtin_amdgcn_mfma_f32_16x16x32_bf16(pa1, vb, o0, 0, 0, 0);
        }
        {
            const short8 va = *(const short8*)&lV[(1 * 16 + l15) * 72 + quad * 8];
            const short8 vb = *(const short8*)&lV[(1 * 16 + l15) * 72 + 32 + quad * 8];
            o1 = __builtin_amdgcn_mfma_f32_16x16x32_bf16(pa0, va, o1, 0, 0, 0);
            o1 = __builtin_amdgcn_mfma_f32_16x16x32_bf16(pa1, vb, o1, 0, 0, 0);
        }
        {
            const short8 va = *(const short8*)&lV[(2 * 16 + l15) * 72 + quad * 8];
            const short8 vb = *(const short8*)&lV[(2 * 16 + l15) * 72 + 32 + quad * 8];
            o2 = __builtin_amdgcn_mfma_f32_16x16x32_bf16(pa0, va, o2, 0, 0, 0);
            o2 = __builtin_amdgcn_mfma_f32_16x16x32_bf16(pa1, vb, o2, 0, 0, 0);
        }
        {
            const short8 va = *(const short8*)&lV[(3 * 16 + l15) * 72 + quad * 8];
            const short8 vb = *(const short8*)&lV[(3 * 16 + l15) * 72 + 32 + quad * 8];
            o3 = __builtin_amdgcn_mfma_f32_16x16x32_bf16(pa0, va, o3, 0, 0, 0);
            o3 = __builtin_amdgcn_mfma_f32_16x16x32_bf16(pa1, vb, o3, 0, 0, 0);
        }
    }

    lp += __shfl_xor(lp, 16, 64);
    lp += __shfl_xor(lp, 32, 64);

    const int b = bh >> 4, h = bh & 15;
    short* Ap = Ab + ((size_t)(b * SEQ) + q0w + quad * 4) * D_MODEL + h * D_HEAD;
    #pragma unroll
    for (int r = 0; r < 4; r++) {
        const float inv = 1.0f / __shfl(lp, quad * 4 + r, 64);
        Ap[(size_t)r * D_MODEL + l15]      = f2bf(o0[r] * inv);
        Ap[(size_t)r * D_MODEL + 16 + l15] = f2bf(o1[r] * inv);
        Ap[(size_t)r * D_MODEL + 32 + l15] = f2bf(o2[r] * inv);
        Ap[(size_t)r * D_MODEL + 48 + l15] = f2bf(o3[r] * inv);
    }
}

// ---------------------------------------------------------------------------
// Kernel 3: output projection, now on the m97 DMA core.
// ---------------------------------------------------------------------------
__global__ __launch_bounds__(256) void out_mfma_kernel(
    const short* __restrict__ Ab, const short* __restrict__ wob,
    float* __restrict__ out)
{
    __shared__ __align__(16) short smem[8192];   // lA 8KB + lB 8KB

    const int bid = blockIdx.x;
    const int m0 = (bid & 31) * 128;
    const int n0 = (bid >> 5) * 128;

    float4v acc[4][4];
    #pragma unroll
    for (int i = 0; i < 4; i++)
        #pragma unroll
        for (int j = 0; j < 4; j++)
            acc[i][j] = (float4v){0.f, 0.f, 0.f, 0.f};

    gemm_core_lds(Ab, wob, smem, smem + 4096, m0, n0, acc);

    const int tid = threadIdx.x;
    const int lane = tid & 63;
    const int l15 = lane & 15, quad = lane >> 4;
    const int wave = tid >> 6;
    const int mw = (wave & 1) * 64, nw = (wave >> 1) * 64;

    #pragma unroll
    for (int mi = 0; mi < 4; mi++) {
        #pragma unroll
        for (int r = 0; r < 4; r++) {
            const int m = m0 + mw + mi * 16 + quad * 4 + r;
            float* op = out + (size_t)m * D_MODEL + n0 + nw + l15;
            #pragma unroll
            for (int ni = 0; ni < 4; ni++)
                op[ni * 16] = acc[mi][ni][r];
        }
    }
}

// ---------------------------------------------------------------------------
extern "C" void kernel_launch(void* const* d_in, const int* in_sizes, int n_in,
                              void* d_out, int out_size, void* d_ws, size_t ws_size,
                              hipStream_t stream)
{
    const float* x  = (const float*)d_in[0];
    const int*  pos = (const int*)d_in[1];
    const float* wq = (const float*)d_in[2];
    const float* wk = (const float*)d_in[3];
    const float* wv = (const float*)d_in[4];
    const float* wo = (const float*)d_in[5];
    float* out = (float*)d_out;

    const size_t nx = (size_t)BATCH * SEQ * D_MODEL;   // 4M
    const size_t nw = (size_t)D_MODEL * D_MODEL;       // 1M
    short* xb  = (short*)d_ws;
    short* wqb = xb + nx;
    short* wkb = wqb + nw;
    short* wvb = wkb + nw;
    short* wob = wvb + nw;
    short* Qb  = wob + nw;
    short* Kb  = Qb + nx;
    short* Vt  = Kb + nx;
    short* Ab  = Vt + nx;
    float* costab = (float*)(Ab + nx);
    float* sintab = costab + SEQ * 32;

    dim3 blk(256);
    cvt_bf16_kernel<<<dim3(2048, 6), blk, 0, stream>>>(x, wq, wk, wv, wo, pos,
                                                       xb, wqb, wkb, wvb, wob,
                                                       costab, sintab);
    qkv_mfma_kernel<<<dim3(768), blk, 0, stream>>>(xb, wqb, wkb, wvb,
                                                   costab, sintab, Qb, Kb, Vt);
    attn_mfma_kernel<<<dim3(BATCH * NUM_HEADS * (SEQ / 64)), blk, 0, stream>>>(Qb, Kb, Vt, Ab);
    out_mfma_kernel<<<dim3(256), blk, 0, stream>>>(Ab, wob, out);
}

// Round 11
// 198.501 us; speedup vs baseline: 1.0786x; 1.0786x over previous
//
#include <hip/hip_runtime.h>
#include <math.h>

#define D_MODEL 1024
#define NUM_HEADS 16
#define D_HEAD 64
#define SEQ 2048
#define BATCH 2

typedef __attribute__((ext_vector_type(8))) short short8;
typedef __attribute__((ext_vector_type(4))) short short4v;
typedef __attribute__((ext_vector_type(4))) float float4v;

__device__ __forceinline__ short f2bf(float f) {
    unsigned u = __float_as_uint(f);
    u += 0x7FFFu + ((u >> 16) & 1u);
    return (short)(u >> 16);
}

// ---------------------------------------------------------------------------
// Kernel 0: fp32 -> bf16 conversion + RoPE cos/sin table (all libm here;
// NEVER in hot MFMA kernels — R8: sincosf codegen = scratch-spill GBs).
// ---------------------------------------------------------------------------
__global__ __launch_bounds__(256) void cvt_bf16_kernel(
    const float* __restrict__ x,  const float* __restrict__ wq,
    const float* __restrict__ wk, const float* __restrict__ wv,
    const float* __restrict__ wo, const int* __restrict__ pos,
    short* __restrict__ xb,  short* __restrict__ wqb,
    short* __restrict__ wkb, short* __restrict__ wvb,
    short* __restrict__ wob,
    float* __restrict__ costab, float* __restrict__ sintab)
{
    const int a = blockIdx.y;
    if (a == 5) {                          // RoPE table: idx = s*32 + fi
        const int idx = blockIdx.x * 256 + threadIdx.x;
        if (idx < SEQ * 32) {
            const int s = idx >> 5, fi = idx & 31;
            const float p = (float)pos[s];
            const float inv_freq = exp2f((float)fi * -0.4152410118609203f);
            float sn, cs;
            sincosf(p * inv_freq, &sn, &cs);
            costab[idx] = cs;
            sintab[idx] = sn;
        }
        return;
    }
    const float* src = (a == 0) ? x : (a == 1) ? wq : (a == 2) ? wk : (a == 3) ? wv : wo;
    short* dst = (a == 0) ? xb : (a == 1) ? wqb : (a == 2) ? wkb : (a == 3) ? wvb : wob;
    const int n = (a == 0) ? (BATCH * SEQ * D_MODEL) : (D_MODEL * D_MODEL);
    const int i = (blockIdx.x * 256 + threadIdx.x) * 8;
    if (i >= n) return;
    const float4 v0 = *(const float4*)(src + i);
    const float4 v1 = *(const float4*)(src + i + 4);
    short8 r;
    r[0] = f2bf(v0.x); r[1] = f2bf(v0.y); r[2] = f2bf(v0.z); r[3] = f2bf(v0.w);
    r[4] = f2bf(v1.x); r[5] = f2bf(v1.y); r[6] = f2bf(v1.z); r[7] = f2bf(v1.w);
    *(short8*)(dst + i) = r;
}

// ---------------------------------------------------------------------------
// bf16 MFMA GEMM core, register-prefetch + double-buffered LDS (R9 version —
// best measured: 537 TF effective. R10 showed the m97 global_load_lds core
// LOSES here: short K-loop (32 steps) can't amortize its vmcnt(0) barrier
// drains, and VGPR 128->148 cost occupancy).
// ---------------------------------------------------------------------------
__device__ __forceinline__ void gemm_core_db(
    const short* __restrict__ a, const short* __restrict__ b,
    short* smem, int m0, int n0, float4v acc[4][4])
{
    const int tid = threadIdx.x;
    const int lane = tid & 63;
    const int l15 = lane & 15, quad = lane >> 4;
    const int wave = tid >> 6;
    const int mw = (wave & 1) * 64, nw = (wave >> 1) * 64;
    const int srow = tid >> 2;
    const int scol = (tid & 3) * 8;

    const short* ag = a + (size_t)(m0 + srow) * D_MODEL + scol;
    const short* bg = b + (size_t)(n0 + srow) * D_MODEL + scol;

    short* bufA[2] = { smem,        smem + 8192 };
    short* bufB[2] = { smem + 4096, smem + 12288 };

    short8 ga0 = *(const short8*)(ag);
    short8 ga1 = *(const short8*)(ag + (size_t)64 * D_MODEL);
    short8 gb0 = *(const short8*)(bg);
    short8 gb1 = *(const short8*)(bg + (size_t)64 * D_MODEL);
    *(short8*)&bufA[0][srow * 32 + scol]        = ga0;
    *(short8*)&bufA[0][(64 + srow) * 32 + scol] = ga1;
    *(short8*)&bufB[0][srow * 32 + scol]        = gb0;
    *(short8*)&bufB[0][(64 + srow) * 32 + scol] = gb1;
    ga0 = *(const short8*)(ag + 32);
    ga1 = *(const short8*)(ag + 32 + (size_t)64 * D_MODEL);
    gb0 = *(const short8*)(bg + 32);
    gb1 = *(const short8*)(bg + 32 + (size_t)64 * D_MODEL);

    for (int k = 0; k < 32; k++) {
        __syncthreads();
        if (k + 1 < 32) {
            short* bA = bufA[(k + 1) & 1];
            short* bB = bufB[(k + 1) & 1];
            *(short8*)&bA[srow * 32 + scol]        = ga0;
            *(short8*)&bA[(64 + srow) * 32 + scol] = ga1;
            *(short8*)&bB[srow * 32 + scol]        = gb0;
            *(short8*)&bB[(64 + srow) * 32 + scol] = gb1;
        }
        if (k + 2 < 32) {
            const int off = (k + 2) * 32;
            ga0 = *(const short8*)(ag + off);
            ga1 = *(const short8*)(ag + off + (size_t)64 * D_MODEL);
            gb0 = *(const short8*)(bg + off);
            gb1 = *(const short8*)(bg + off + (size_t)64 * D_MODEL);
        }
        const short* lA = bufA[k & 1];
        const short* lB = bufB[k & 1];
        short8 af[4], bf[4];
        #pragma unroll
        for (int i = 0; i < 4; i++)
            af[i] = *(const short8*)&lA[(mw + i * 16 + l15) * 32 + quad * 8];
        #pragma unroll
        for (int i = 0; i < 4; i++)
            bf[i] = *(const short8*)&lB[(nw + i * 16 + l15) * 32 + quad * 8];
        #pragma unroll
        for (int mi = 0; mi < 4; mi++)
            #pragma unroll
            for (int ni = 0; ni < 4; ni++)
                acc[mi][ni] = __builtin_amdgcn_mfma_f32_16x16x32_bf16(
                    af[mi], bf[ni], acc[mi][ni], 0, 0, 0);
    }
}

// ---------------------------------------------------------------------------
// Kernel 1: fused QKV projection (R9 version — best measured, 48 us).
// ---------------------------------------------------------------------------
__global__ __launch_bounds__(256) void qkv_mfma_kernel(
    const short* __restrict__ xb, const short* __restrict__ wqb,
    const short* __restrict__ wkb, const short* __restrict__ wvb,
    const float* __restrict__ costab, const float* __restrict__ sintab,
    short* __restrict__ Qb, short* __restrict__ Kb, short* __restrict__ Vt)
{
    __shared__ __align__(16) short smem[128 * 136];

    const int z = blockIdx.x >> 8;
    const int bid = blockIdx.x & 255;
    const int m0 = (bid & 31) * 128;
    const int n0 = (bid >> 5) * 128;
    const short* w = (z == 0) ? wqb : (z == 1) ? wkb : wvb;

    float4v acc[4][4];
    #pragma unroll
    for (int i = 0; i < 4; i++)
        #pragma unroll
        for (int j = 0; j < 4; j++)
            acc[i][j] = (float4v){0.f, 0.f, 0.f, 0.f};

    gemm_core_db(xb, w, smem, m0, n0, acc);

    const int tid = threadIdx.x;
    const int lane = tid & 63;
    const int l15 = lane & 15, quad = lane >> 4;
    const int wave = tid >> 6;
    const int mw = (wave & 1) * 64, nw = (wave >> 1) * 64;
    const int s_base = m0 & (SEQ - 1);
    const int bb = m0 >> 11;

    __syncthreads();

    if (z == 2) {
        #pragma unroll
        for (int ni = 0; ni < 4; ni++) {
            #pragma unroll
            for (int mi = 0; mi < 4; mi++) {
                #pragma unroll
                for (int r = 0; r < 4; r++)
                    smem[(nw + ni * 16 + l15) * 136 + mw + mi * 16 + quad * 4 + r] =
                        f2bf(acc[mi][ni][r]);
            }
        }
        __syncthreads();
        #pragma unroll
        for (int it = 0; it < 8; it++) {
            const int nloc = it * 16 + (tid >> 4);
            const int mloc = (tid & 15) * 8;
            const short8 val = *(const short8*)&smem[nloc * 136 + mloc];
            const int n = n0 + nloc;
            const int h = n >> 6, d = n & 63;
            *(short8*)(Vt + ((size_t)(bb * NUM_HEADS + h) * D_HEAD + d) * SEQ +
                       s_base + mloc) = val;
        }
    } else {
        short* dst = (z == 0) ? Qb : Kb;
        const float qs = (z == 0) ? 0.125f : 1.0f;
        #pragma unroll
        for (int ni = 0; ni < 4; ni++) {
            const int n = n0 + nw + ni * 16 + l15;
            const int d = n & 63;
            const int fi = d >> 1;
            #pragma unroll
            for (int mi = 0; mi < 4; mi++) {
                #pragma unroll
                for (int r = 0; r < 4; r++) {
                    const int mloc = mw + mi * 16 + quad * 4 + r;
                    const int ti = ((s_base + mloc) << 5) + fi;
                    const float cs = costab[ti];
                    const float sn = sintab[ti];
                    const float val = acc[mi][ni][r];
                    const float partner = __shfl_xor(val, 1, 64);
                    const float res = (l15 & 1) ? fmaf(partner, sn, val * cs)
                                                : fmaf(val, cs, -partner * sn);
                    smem[mloc * 136 + nw + ni * 16 + l15] = f2bf(res * qs);
                }
            }
        }
        __syncthreads();
        #pragma unroll
        for (int it = 0; it < 8; it++) {
            const int ri = it * 32 + (tid >> 3);
            const int mloc = ri & 127;
            const int hh = ri >> 7;
            const int nloc = hh * 64 + (tid & 7) * 8;
            const short8 val = *(const short8*)&smem[mloc * 136 + nloc];
            const int n = n0 + nloc;
            const int h = n >> 6, d = n & 63;
            *(short8*)(dst + ((size_t)(bb * NUM_HEADS + h) * SEQ + s_base + mloc) *
                       D_HEAD + d) = val;
        }
    }
}

// ---------------------------------------------------------------------------
// Kernel 2: causal flash attention. R11 change: 128 q-rows per block (each
// wave owns TWO 16-row sets, 64 apart) -> tile-iterations 528->272 per bh;
// each staged 64-key tile now feeds 32 MFMAs instead of 16, and total K/V
// re-reads halve. 512 blocks, LDS 54 KB (2 blocks/CU).
// ---------------------------------------------------------------------------
__global__ __launch_bounds__(256) void attn_mfma_kernel(
    const short* __restrict__ Qb, const short* __restrict__ Kb,
    const short* __restrict__ Vt, short* __restrict__ Ab)
{
    __shared__ __align__(16) short lK[64 * 72];
    __shared__ __align__(16) short lV[64 * 72];
    __shared__ __align__(16) short lPA[4][16 * 72];
    __shared__ __align__(16) short lPB[4][16 * 72];

    const int tid = threadIdx.x;
    const int lane = tid & 63;
    const int wave = tid >> 6;
    const int l15 = lane & 15;
    const int quad = lane >> 4;

    const int bh = blockIdx.x & (BATCH * NUM_HEADS - 1);
    const int qt = (SEQ / 128 - 1) - (blockIdx.x >> 5);   // longest first
    const int q0b = qt * 128;
    const int qA = q0b + wave * 16;        // set A row base
    const int qB = qA + 64;                // set B row base
    const int qcA = qA + l15;              // per-lane causal bound (S^T: q=l15)
    const int qcB = qB + l15;

    const short* Kg = Kb + (size_t)bh * SEQ * D_HEAD;
    const short* Vg = Vt + (size_t)bh * D_HEAD * SEQ;

    const short* QrowA = Qb + ((size_t)bh * SEQ + qA + l15) * D_HEAD;
    const short8 qa0 = *(const short8*)(QrowA + quad * 8);
    const short8 qa1 = *(const short8*)(QrowA + 32 + quad * 8);
    const short* QrowB = Qb + ((size_t)bh * SEQ + qB + l15) * D_HEAD;
    const short8 qb0 = *(const short8*)(QrowB + quad * 8);
    const short8 qb1 = *(const short8*)(QrowB + 32 + quad * 8);

    float4v oA0 = {0.f,0.f,0.f,0.f}, oA1 = oA0, oA2 = oA0, oA3 = oA0;
    float4v oB0 = oA0, oB1 = oA0, oB2 = oA0, oB3 = oA0;
    float lpA = 0.f, lpB = 0.f;

    const int nt = (qt + 1) * 2;           // 64-key tiles covering q0b+127
    const int srow = tid >> 2;             // 0..63
    const int sch = (tid & 3) * 8;         // 0,8,16,24 shorts

    short8 k0 = *(const short8*)(Kg + (size_t)srow * D_HEAD + sch);
    short8 k1 = *(const short8*)(Kg + (size_t)srow * D_HEAD + sch + 32);
    short8 v0 = *(const short8*)(Vg + (size_t)srow * SEQ + sch);
    short8 v1 = *(const short8*)(Vg + (size_t)srow * SEQ + sch + 32);

    for (int t = 0; t < nt; t++) {
        const int kt0 = t * 64;
        __syncthreads();
        *(short8*)&lK[srow * 72 + sch]      = k0;
        *(short8*)&lK[srow * 72 + sch + 32] = k1;
        *(short8*)&lV[srow * 72 + sch]      = v0;
        *(short8*)&lV[srow * 72 + sch + 32] = v1;
        __syncthreads();
        if (t + 1 < nt) {
            k0 = *(const short8*)(Kg + (size_t)(kt0 + 64 + srow) * D_HEAD + sch);
            k1 = *(const short8*)(Kg + (size_t)(kt0 + 64 + srow) * D_HEAD + sch + 32);
            v0 = *(const short8*)(Vg + (size_t)srow * SEQ + kt0 + 64 + sch);
            v1 = *(const short8*)(Vg + (size_t)srow * SEQ + kt0 + 64 + sch + 32);
        }

        const bool actA = (kt0 <= qA + 15);   // wave-uniform

        // S^T = K Q^T per 16-key group g, both q-sets
        #pragma unroll
        for (int g = 0; g < 4; g++) {
            const short8 ka = *(const short8*)&lK[(g * 16 + l15) * 72 + quad * 8];
            const short8 kb = *(const short8*)&lK[(g * 16 + l15) * 72 + 32 + quad * 8];
            const int kbase = kt0 + g * 16 + quad * 4;

            if (actA) {
                float4v s = {0.f, 0.f, 0.f, 0.f};
                s = __builtin_amdgcn_mfma_f32_16x16x32_bf16(ka, qa0, s, 0, 0, 0);
                s = __builtin_amdgcn_mfma_f32_16x16x32_bf16(kb, qa1, s, 0, 0, 0);
                short4v pk;
                #pragma unroll
                for (int r = 0; r < 4; r++) {
                    const float e = (kbase + r <= qcA) ? __expf(s[r]) : 0.f;
                    lpA += e;
                    pk[r] = f2bf(e);
                }
                *(short4v*)&lPA[wave][l15 * 72 + g * 16 + quad * 4] = pk;
            }
            {
                float4v s = {0.f, 0.f, 0.f, 0.f};
                s = __builtin_amdgcn_mfma_f32_16x16x32_bf16(ka, qb0, s, 0, 0, 0);
                s = __builtin_amdgcn_mfma_f32_16x16x32_bf16(kb, qb1, s, 0, 0, 0);
                short4v pk;
                #pragma unroll
                for (int r = 0; r < 4; r++) {
                    const float e = (kbase + r <= qcB) ? __expf(s[r]) : 0.f;
                    lpB += e;
                    pk[r] = f2bf(e);
                }
                *(short4v*)&lPB[wave][l15 * 72 + g * 16 + quad * 4] = pk;
            }
        }

        const short8 pb0 = *(const short8*)&lPB[wave][l15 * 72 + quad * 8];
        const short8 pb1 = *(const short8*)&lPB[wave][l15 * 72 + 32 + quad * 8];
        if (actA) {
            const short8 pa0 = *(const short8*)&lPA[wave][l15 * 72 + quad * 8];
            const short8 pa1 = *(const short8*)&lPA[wave][l15 * 72 + 32 + quad * 8];
            #pragma unroll
            for (int gg = 0; gg < 4; gg++) {
                const short8 va = *(const short8*)&lV[(gg * 16 + l15) * 72 + quad * 8];
                const short8 vb = *(const short8*)&lV[(gg * 16 + l15) * 72 + 32 + quad * 8];
                float4v* oA = (gg == 0) ? &oA0 : (gg == 1) ? &oA1 : (gg == 2) ? &oA2 : &oA3;
                float4v* oB = (gg == 0) ? &oB0 : (gg == 1) ? &oB1 : (gg == 2) ? &oB2 : &oB3;
                *oA = __builtin_amdgcn_mfma_f32_16x16x32_bf16(pa0, va, *oA, 0, 0, 0);
                *oA = __builtin_amdgcn_mfma_f32_16x16x32_bf16(pa1, vb, *oA, 0, 0, 0);
                *oB = __builtin_amdgcn_mfma_f32_16x16x32_bf16(pb0, va, *oB, 0, 0, 0);
                *oB = __builtin_amdgcn_mfma_f32_16x16x32_bf16(pb1, vb, *oB, 0, 0, 0);
            }
        } else {
            #pragma unroll
            for (int gg = 0; gg < 4; gg++) {
                const short8 va = *(const short8*)&lV[(gg * 16 + l15) * 72 + quad * 8];
                const short8 vb = *(const short8*)&lV[(gg * 16 + l15) * 72 + 32 + quad * 8];
                float4v* oB = (gg == 0) ? &oB0 : (gg == 1) ? &oB1 : (gg == 2) ? &oB2 : &oB3;
                *oB = __builtin_amdgcn_mfma_f32_16x16x32_bf16(pb0, va, *oB, 0, 0, 0);
                *oB = __builtin_amdgcn_mfma_f32_16x16x32_bf16(pb1, vb, *oB, 0, 0, 0);
            }
        }
    }

    lpA += __shfl_xor(lpA, 16, 64);
    lpA += __shfl_xor(lpA, 32, 64);
    lpB += __shfl_xor(lpB, 16, 64);
    lpB += __shfl_xor(lpB, 32, 64);

    const int b = bh >> 4, h = bh & 15;
    short* ApA = Ab + ((size_t)(b * SEQ) + qA + quad * 4) * D_MODEL + h * D_HEAD;
    short* ApB = Ab + ((size_t)(b * SEQ) + qB + quad * 4) * D_MODEL + h * D_HEAD;
    #pragma unroll
    for (int r = 0; r < 4; r++) {
        const float invA = 1.0f / __shfl(lpA, quad * 4 + r, 64);
        ApA[(size_t)r * D_MODEL + l15]      = f2bf(oA0[r] * invA);
        ApA[(size_t)r * D_MODEL + 16 + l15] = f2bf(oA1[r] * invA);
        ApA[(size_t)r * D_MODEL + 32 + l15] = f2bf(oA2[r] * invA);
        ApA[(size_t)r * D_MODEL + 48 + l15] = f2bf(oA3[r] * invA);
        const float invB = 1.0f / __shfl(lpB, quad * 4 + r, 64);
        ApB[(size_t)r * D_MODEL + l15]      = f2bf(oB0[r] * invB);
        ApB[(size_t)r * D_MODEL + 16 + l15] = f2bf(oB1[r] * invB);
        ApB[(size_t)r * D_MODEL + 32 + l15] = f2bf(oB2[r] * invB);
        ApB[(size_t)r * D_MODEL + 48 + l15] = f2bf(oB3[r] * invB);
    }
}

// ---------------------------------------------------------------------------
// Kernel 3: output projection (R9 version — reg-dbuf core).
// ---------------------------------------------------------------------------
__global__ __launch_bounds__(256) void out_mfma_kernel(
    const short* __restrict__ Ab, const short* __restrict__ wob,
    float* __restrict__ out)
{
    __shared__ __align__(16) short smem[2 * 8192];

    const int bid = blockIdx.x;
    const int m0 = (bid & 31) * 128;
    const int n0 = (bid >> 5) * 128;

    float4v acc[4][4];
    #pragma unroll
    for (int i = 0; i < 4; i++)
        #pragma unroll
        for (int j = 0; j < 4; j++)
            acc[i][j] = (float4v){0.f, 0.f, 0.f, 0.f};

    gemm_core_db(Ab, wob, smem, m0, n0, acc);

    const int tid = threadIdx.x;
    const int lane = tid & 63;
    const int l15 = lane & 15, quad = lane >> 4;
    const int wave = tid >> 6;
    const int mw = (wave & 1) * 64, nw = (wave >> 1) * 64;

    #pragma unroll
    for (int mi = 0; mi < 4; mi++) {
        #pragma unroll
        for (int r = 0; r < 4; r++) {
            const int m = m0 + mw + mi * 16 + quad * 4 + r;
            float* op = out + (size_t)m * D_MODEL + n0 + nw + l15;
            #pragma unroll
            for (int ni = 0; ni < 4; ni++)
                op[ni * 16] = acc[mi][ni][r];
        }
    }
}

// ---------------------------------------------------------------------------
extern "C" void kernel_launch(void* const* d_in, const int* in_sizes, int n_in,
                              void* d_out, int out_size, void* d_ws, size_t ws_size,
                              hipStream_t stream)
{
    const float* x  = (const float*)d_in[0];
    const int*  pos = (const int*)d_in[1];
    const float* wq = (const float*)d_in[2];
    const float* wk = (const float*)d_in[3];
    const float* wv = (const float*)d_in[4];
    const float* wo = (const float*)d_in[5];
    float* out = (float*)d_out;

    const size_t nx = (size_t)BATCH * SEQ * D_MODEL;   // 4M
    const size_t nw = (size_t)D_MODEL * D_MODEL;       // 1M
    short* xb  = (short*)d_ws;
    short* wqb = xb + nx;
    short* wkb = wqb + nw;
    short* wvb = wkb + nw;
    short* wob = wvb + nw;
    short* Qb  = wob + nw;
    short* Kb  = Qb + nx;
    short* Vt  = Kb + nx;
    short* Ab  = Vt + nx;
    float* costab = (float*)(Ab + nx);
    float* sintab = costab + SEQ * 32;

    dim3 blk(256);
    cvt_bf16_kernel<<<dim3(2048, 6), blk, 0, stream>>>(x, wq, wk, wv, wo, pos,
                                                       xb, wqb, wkb, wvb, wob,
                                                       costab, sintab);
    qkv_mfma_kernel<<<dim3(768), blk, 0, stream>>>(xb, wqb, wkb, wvb,
                                                   costab, sintab, Qb, Kb, Vt);
    attn_mfma_kernel<<<dim3(BATCH * NUM_HEADS * (SEQ / 128)), blk, 0, stream>>>(Qb, Kb, Vt, Ab);
    out_mfma_kernel<<<dim3(256), blk, 0, stream>>>(Ab, wob, out);
}

// Round 12
// 188.853 us; speedup vs baseline: 1.1337x; 1.0511x over previous
//
#include <hip/hip_runtime.h>
#include <math.h>

#define D_MODEL 1024
#define NUM_HEADS 16
#define D_HEAD 64
#define SEQ 2048
#define BATCH 2

typedef __attribute__((ext_vector_type(8))) short short8;
typedef __attribute__((ext_vector_type(4))) short short4v;
typedef __attribute__((ext_vector_type(4))) float float4v;

__device__ __forceinline__ short f2bf(float f) {
    unsigned u = __float_as_uint(f);
    u += 0x7FFFu + ((u >> 16) & 1u);
    return (short)(u >> 16);
}

// ---------------------------------------------------------------------------
// Kernel 0: fp32 -> bf16 conversion + RoPE cos/sin table. Exact-sized 1-D
// grid (R12: was a padded 2-D grid with ~2/3 empty blocks). All libm here;
// NEVER in hot MFMA kernels (R8: sincosf codegen = scratch-spill GBs).
// Block map: [0,512) wq | [512,1024) wk | [1024,1536) wv | [1536,2048) wo |
//            [2048,4096) x | [4096,4352) rope table.
// ---------------------------------------------------------------------------
__global__ __launch_bounds__(256) void cvt_bf16_kernel(
    const float* __restrict__ x,  const float* __restrict__ wq,
    const float* __restrict__ wk, const float* __restrict__ wv,
    const float* __restrict__ wo, const int* __restrict__ pos,
    short* __restrict__ xb,  short* __restrict__ wqb,
    short* __restrict__ wkb, short* __restrict__ wvb,
    short* __restrict__ wob,
    float* __restrict__ costab, float* __restrict__ sintab)
{
    const int bidx = blockIdx.x;
    if (bidx >= 4096) {                    // RoPE table: idx = s*32 + fi
        const int idx = (bidx - 4096) * 256 + threadIdx.x;
        const int s = idx >> 5, fi = idx & 31;
        const float p = (float)pos[s];
        const float inv_freq = exp2f((float)fi * -0.4152410118609203f);
        float sn, cs;
        sincosf(p * inv_freq, &sn, &cs);
        costab[idx] = cs;
        sintab[idx] = sn;
        return;
    }
    const float* src;
    short* dst;
    int base;
    if (bidx < 2048) {
        const int a = bidx >> 9;           // 0..3 -> wq,wk,wv,wo
        src = (a == 0) ? wq : (a == 1) ? wk : (a == 2) ? wv : wo;
        dst = (a == 0) ? wqb : (a == 1) ? wkb : (a == 2) ? wvb : wob;
        base = (bidx & 511) * 2048;
    } else {
        src = x;
        dst = xb;
        base = (bidx - 2048) * 2048;
    }
    const int i = base + threadIdx.x * 8;
    const float4 v0 = *(const float4*)(src + i);
    const float4 v1 = *(const float4*)(src + i + 4);
    short8 r;
    r[0] = f2bf(v0.x); r[1] = f2bf(v0.y); r[2] = f2bf(v0.z); r[3] = f2bf(v0.w);
    r[4] = f2bf(v1.x); r[5] = f2bf(v1.y); r[6] = f2bf(v1.z); r[7] = f2bf(v1.w);
    *(short8*)(dst + i) = r;
}

// ---------------------------------------------------------------------------
// bf16 MFMA GEMM core, register-prefetch + double-buffered LDS (R9 — best
// measured 537 TF effective; R10 proved the global_load_lds core loses on
// short K-loops).
// ---------------------------------------------------------------------------
__device__ __forceinline__ void gemm_core_db(
    const short* __restrict__ a, const short* __restrict__ b,
    short* smem, int m0, int n0, float4v acc[4][4])
{
    const int tid = threadIdx.x;
    const int lane = tid & 63;
    const int l15 = lane & 15, quad = lane >> 4;
    const int wave = tid >> 6;
    const int mw = (wave & 1) * 64, nw = (wave >> 1) * 64;
    const int srow = tid >> 2;
    const int scol = (tid & 3) * 8;

    const short* ag = a + (size_t)(m0 + srow) * D_MODEL + scol;
    const short* bg = b + (size_t)(n0 + srow) * D_MODEL + scol;

    short* bufA[2] = { smem,        smem + 8192 };
    short* bufB[2] = { smem + 4096, smem + 12288 };

    short8 ga0 = *(const short8*)(ag);
    short8 ga1 = *(const short8*)(ag + (size_t)64 * D_MODEL);
    short8 gb0 = *(const short8*)(bg);
    short8 gb1 = *(const short8*)(bg + (size_t)64 * D_MODEL);
    *(short8*)&bufA[0][srow * 32 + scol]        = ga0;
    *(short8*)&bufA[0][(64 + srow) * 32 + scol] = ga1;
    *(short8*)&bufB[0][srow * 32 + scol]        = gb0;
    *(short8*)&bufB[0][(64 + srow) * 32 + scol] = gb1;
    ga0 = *(const short8*)(ag + 32);
    ga1 = *(const short8*)(ag + 32 + (size_t)64 * D_MODEL);
    gb0 = *(const short8*)(bg + 32);
    gb1 = *(const short8*)(bg + 32 + (size_t)64 * D_MODEL);

    for (int k = 0; k < 32; k++) {
        __syncthreads();
        if (k + 1 < 32) {
            short* bA = bufA[(k + 1) & 1];
            short* bB = bufB[(k + 1) & 1];
            *(short8*)&bA[srow * 32 + scol]        = ga0;
            *(short8*)&bA[(64 + srow) * 32 + scol] = ga1;
            *(short8*)&bB[srow * 32 + scol]        = gb0;
            *(short8*)&bB[(64 + srow) * 32 + scol] = gb1;
        }
        if (k + 2 < 32) {
            const int off = (k + 2) * 32;
            ga0 = *(const short8*)(ag + off);
            ga1 = *(const short8*)(ag + off + (size_t)64 * D_MODEL);
            gb0 = *(const short8*)(bg + off);
            gb1 = *(const short8*)(bg + off + (size_t)64 * D_MODEL);
        }
        const short* lA = bufA[k & 1];
        const short* lB = bufB[k & 1];
        short8 af[4], bf[4];
        #pragma unroll
        for (int i = 0; i < 4; i++)
            af[i] = *(const short8*)&lA[(mw + i * 16 + l15) * 32 + quad * 8];
        #pragma unroll
        for (int i = 0; i < 4; i++)
            bf[i] = *(const short8*)&lB[(nw + i * 16 + l15) * 32 + quad * 8];
        #pragma unroll
        for (int mi = 0; mi < 4; mi++)
            #pragma unroll
            for (int ni = 0; ni < 4; ni++)
                acc[mi][ni] = __builtin_amdgcn_mfma_f32_16x16x32_bf16(
                    af[mi], bf[ni], acc[mi][ni], 0, 0, 0);
    }
}

// ---------------------------------------------------------------------------
// Kernel 1: fused QKV projection (R9 — best measured, 48 us).
// ---------------------------------------------------------------------------
__global__ __launch_bounds__(256) void qkv_mfma_kernel(
    const short* __restrict__ xb, const short* __restrict__ wqb,
    const short* __restrict__ wkb, const short* __restrict__ wvb,
    const float* __restrict__ costab, const float* __restrict__ sintab,
    short* __restrict__ Qb, short* __restrict__ Kb, short* __restrict__ Vt)
{
    __shared__ __align__(16) short smem[128 * 136];

    const int z = blockIdx.x >> 8;
    const int bid = blockIdx.x & 255;
    const int m0 = (bid & 31) * 128;
    const int n0 = (bid >> 5) * 128;
    const short* w = (z == 0) ? wqb : (z == 1) ? wkb : wvb;

    float4v acc[4][4];
    #pragma unroll
    for (int i = 0; i < 4; i++)
        #pragma unroll
        for (int j = 0; j < 4; j++)
            acc[i][j] = (float4v){0.f, 0.f, 0.f, 0.f};

    gemm_core_db(xb, w, smem, m0, n0, acc);

    const int tid = threadIdx.x;
    const int lane = tid & 63;
    const int l15 = lane & 15, quad = lane >> 4;
    const int wave = tid >> 6;
    const int mw = (wave & 1) * 64, nw = (wave >> 1) * 64;
    const int s_base = m0 & (SEQ - 1);
    const int bb = m0 >> 11;

    __syncthreads();

    if (z == 2) {
        #pragma unroll
        for (int ni = 0; ni < 4; ni++) {
            #pragma unroll
            for (int mi = 0; mi < 4; mi++) {
                #pragma unroll
                for (int r = 0; r < 4; r++)
                    smem[(nw + ni * 16 + l15) * 136 + mw + mi * 16 + quad * 4 + r] =
                        f2bf(acc[mi][ni][r]);
            }
        }
        __syncthreads();
        #pragma unroll
        for (int it = 0; it < 8; it++) {
            const int nloc = it * 16 + (tid >> 4);
            const int mloc = (tid & 15) * 8;
            const short8 val = *(const short8*)&smem[nloc * 136 + mloc];
            const int n = n0 + nloc;
            const int h = n >> 6, d = n & 63;
            *(short8*)(Vt + ((size_t)(bb * NUM_HEADS + h) * D_HEAD + d) * SEQ +
                       s_base + mloc) = val;
        }
    } else {
        short* dst = (z == 0) ? Qb : Kb;
        const float qs = (z == 0) ? 0.125f : 1.0f;
        #pragma unroll
        for (int ni = 0; ni < 4; ni++) {
            const int n = n0 + nw + ni * 16 + l15;
            const int d = n & 63;
            const int fi = d >> 1;
            #pragma unroll
            for (int mi = 0; mi < 4; mi++) {
                #pragma unroll
                for (int r = 0; r < 4; r++) {
                    const int mloc = mw + mi * 16 + quad * 4 + r;
                    const int ti = ((s_base + mloc) << 5) + fi;
                    const float cs = costab[ti];
                    const float sn = sintab[ti];
                    const float val = acc[mi][ni][r];
                    const float partner = __shfl_xor(val, 1, 64);
                    const float res = (l15 & 1) ? fmaf(partner, sn, val * cs)
                                                : fmaf(val, cs, -partner * sn);
                    smem[mloc * 136 + nw + ni * 16 + l15] = f2bf(res * qs);
                }
            }
        }
        __syncthreads();
        #pragma unroll
        for (int it = 0; it < 8; it++) {
            const int ri = it * 32 + (tid >> 3);
            const int mloc = ri & 127;
            const int hh = ri >> 7;
            const int nloc = hh * 64 + (tid & 7) * 8;
            const short8 val = *(const short8*)&smem[mloc * 136 + nloc];
            const int n = n0 + nloc;
            const int h = n >> 6, d = n & 63;
            *(short8*)(dst + ((size_t)(bb * NUM_HEADS + h) * SEQ + s_base + mloc) *
                       D_HEAD + d) = val;
        }
    }
}

// ---------------------------------------------------------------------------
// Kernel 2: causal flash attention — exact R9 shape (best measured; R11's
// 128-row Q-tile regressed: VALU-bound kernel, B-set exp work over every
// tile + tail imbalance at 512 blocks).
// ---------------------------------------------------------------------------
__global__ __launch_bounds__(256) void attn_mfma_kernel(
    const short* __restrict__ Qb, const short* __restrict__ Kb,
    const short* __restrict__ Vt, short* __restrict__ Ab)
{
    __shared__ __align__(16) short lK[64 * 72];
    __shared__ __align__(16) short lV[64 * 72];
    __shared__ __align__(16) short lP[4][16 * 72];

    const int tid = threadIdx.x;
    const int lane = tid & 63;
    const int wave = tid >> 6;
    const int l15 = lane & 15;
    const int quad = lane >> 4;

    const int bh = blockIdx.x & (BATCH * NUM_HEADS - 1);
    const int qt = (SEQ / 64 - 1) - (blockIdx.x >> 5);   // longest first
    const int q0w = qt * 64 + wave * 16;
    const int qcmp = q0w + l15;

    const short* Kg = Kb + (size_t)bh * SEQ * D_HEAD;
    const short* Vg = Vt + (size_t)bh * D_HEAD * SEQ;

    const short* Qrow = Qb + ((size_t)bh * SEQ + q0w + l15) * D_HEAD;
    const short8 qf0 = *(const short8*)(Qrow + quad * 8);
    const short8 qf1 = *(const short8*)(Qrow + 32 + quad * 8);

    float4v o0 = {0.f, 0.f, 0.f, 0.f}, o1 = o0, o2 = o0, o3 = o0;
    float lp = 0.f;

    const int nt = qt + 1;                 // 64-key tiles
    const int srow = tid >> 2;             // 0..63
    const int sch = (tid & 3) * 8;         // 0,8,16,24 shorts

    short8 k0 = *(const short8*)(Kg + (size_t)srow * D_HEAD + sch);
    short8 k1 = *(const short8*)(Kg + (size_t)srow * D_HEAD + sch + 32);
    short8 v0 = *(const short8*)(Vg + (size_t)srow * SEQ + sch);
    short8 v1 = *(const short8*)(Vg + (size_t)srow * SEQ + sch + 32);

    for (int t = 0; t < nt; t++) {
        const int kt0 = t * 64;
        __syncthreads();
        *(short8*)&lK[srow * 72 + sch]      = k0;
        *(short8*)&lK[srow * 72 + sch + 32] = k1;
        *(short8*)&lV[srow * 72 + sch]      = v0;
        *(short8*)&lV[srow * 72 + sch + 32] = v1;
        __syncthreads();
        if (t + 1 < nt) {
            k0 = *(const short8*)(Kg + (size_t)(kt0 + 64 + srow) * D_HEAD + sch);
            k1 = *(const short8*)(Kg + (size_t)(kt0 + 64 + srow) * D_HEAD + sch + 32);
            v0 = *(const short8*)(Vg + (size_t)srow * SEQ + kt0 + 64 + sch);
            v1 = *(const short8*)(Vg + (size_t)srow * SEQ + kt0 + 64 + sch + 32);
        }

        short* Pw = lP[wave];
        #pragma unroll
        for (int g = 0; g < 4; g++) {
            float4v s = {0.f, 0.f, 0.f, 0.f};
            const short8 ka = *(const short8*)&lK[(g * 16 + l15) * 72 + quad * 8];
            s = __builtin_amdgcn_mfma_f32_16x16x32_bf16(ka, qf0, s, 0, 0, 0);
            const short8 kb = *(const short8*)&lK[(g * 16 + l15) * 72 + 32 + quad * 8];
            s = __builtin_amdgcn_mfma_f32_16x16x32_bf16(kb, qf1, s, 0, 0, 0);

            const int kbase = kt0 + g * 16 + quad * 4;
            short4v pk;
            #pragma unroll
            for (int r = 0; r < 4; r++) {
                const float e = (kbase + r <= qcmp) ? __expf(s[r]) : 0.f;
                lp += e;
                pk[r] = f2bf(e);
            }
            *(short4v*)&Pw[l15 * 72 + g * 16 + quad * 4] = pk;
        }

        const short8 pa0 = *(const short8*)&lP[wave][l15 * 72 + quad * 8];
        const short8 pa1 = *(const short8*)&lP[wave][l15 * 72 + 32 + quad * 8];

        {
            const short8 va = *(const short8*)&lV[(0 * 16 + l15) * 72 + quad * 8];
            const short8 vb = *(const short8*)&lV[(0 * 16 + l15) * 72 + 32 + quad * 8];
            o0 = __builtin_amdgcn_mfma_f32_16x16x32_bf16(pa0, va, o0, 0, 0, 0);
            o0 = __builtin_amdgcn_mfma_f32_16x16x32_bf16(pa1, vb, o0, 0, 0, 0);
        }
        {
            const short8 va = *(const short8*)&lV[(1 * 16 + l15) * 72 + quad * 8];
            const short8 vb = *(const short8*)&lV[(1 * 16 + l15) * 72 + 32 + quad * 8];
            o1 = __builtin_amdgcn_mfma_f32_16x16x32_bf16(pa0, va, o1, 0, 0, 0);
            o1 = __builtin_amdgcn_mfma_f32_16x16x32_bf16(pa1, vb, o1, 0, 0, 0);
        }
        {
            const short8 va = *(const short8*)&lV[(2 * 16 + l15) * 72 + quad * 8];
            const short8 vb = *(const short8*)&lV[(2 * 16 + l15) * 72 + 32 + quad * 8];
            o2 = __builtin_amdgcn_mfma_f32_16x16x32_bf16(pa0, va, o2, 0, 0, 0);
            o2 = __builtin_amdgcn_mfma_f32_16x16x32_bf16(pa1, vb, o2, 0, 0, 0);
        }
        {
            const short8 va = *(const short8*)&lV[(3 * 16 + l15) * 72 + quad * 8];
            const short8 vb = *(const short8*)&lV[(3 * 16 + l15) * 72 + 32 + quad * 8];
            o3 = __builtin_amdgcn_mfma_f32_16x16x32_bf16(pa0, va, o3, 0, 0, 0);
            o3 = __builtin_amdgcn_mfma_f32_16x16x32_bf16(pa1, vb, o3, 0, 0, 0);
        }
    }

    lp += __shfl_xor(lp, 16, 64);
    lp += __shfl_xor(lp, 32, 64);

    const int b = bh >> 4, h = bh & 15;
    short* Ap = Ab + ((size_t)(b * SEQ) + q0w + quad * 4) * D_MODEL + h * D_HEAD;
    #pragma unroll
    for (int r = 0; r < 4; r++) {
        const float inv = 1.0f / __shfl(lp, quad * 4 + r, 64);
        Ap[(size_t)r * D_MODEL + l15]      = f2bf(o0[r] * inv);
        Ap[(size_t)r * D_MODEL + 16 + l15] = f2bf(o1[r] * inv);
        Ap[(size_t)r * D_MODEL + 32 + l15] = f2bf(o2[r] * inv);
        Ap[(size_t)r * D_MODEL + 48 + l15] = f2bf(o3[r] * inv);
    }
}

// ---------------------------------------------------------------------------
// Kernel 3: output projection (R9 reg-dbuf core — unchanged).
// ---------------------------------------------------------------------------
__global__ __launch_bounds__(256) void out_mfma_kernel(
    const short* __restrict__ Ab, const short* __restrict__ wob,
    float* __restrict__ out)
{
    __shared__ __align__(16) short smem[2 * 8192];

    const int bid = blockIdx.x;
    const int m0 = (bid & 31) * 128;
    const int n0 = (bid >> 5) * 128;

    float4v acc[4][4];
    #pragma unroll
    for (int i = 0; i < 4; i++)
        #pragma unroll
        for (int j = 0; j < 4; j++)
            acc[i][j] = (float4v){0.f, 0.f, 0.f, 0.f};

    gemm_core_db(Ab, wob, smem, m0, n0, acc);

    const int tid = threadIdx.x;
    const int lane = tid & 63;
    const int l15 = lane & 15, quad = lane >> 4;
    const int wave = tid >> 6;
    const int mw = (wave & 1) * 64, nw = (wave >> 1) * 64;

    #pragma unroll
    for (int mi = 0; mi < 4; mi++) {
        #pragma unroll
        for (int r = 0; r < 4; r++) {
            const int m = m0 + mw + mi * 16 + quad * 4 + r;
            float* op = out + (size_t)m * D_MODEL + n0 + nw + l15;
            #pragma unroll
            for (int ni = 0; ni < 4; ni++)
                op[ni * 16] = acc[mi][ni][r];
        }
    }
}

// ---------------------------------------------------------------------------
extern "C" void kernel_launch(void* const* d_in, const int* in_sizes, int n_in,
                              void* d_out, int out_size, void* d_ws, size_t ws_size,
                              hipStream_t stream)
{
    const float* x  = (const float*)d_in[0];
    const int*  pos = (const int*)d_in[1];
    const float* wq = (const float*)d_in[2];
    const float* wk = (const float*)d_in[3];
    const float* wv = (const float*)d_in[4];
    const float* wo = (const float*)d_in[5];
    float* out = (float*)d_out;

    const size_t nx = (size_t)BATCH * SEQ * D_MODEL;   // 4M
    const size_t nw = (size_t)D_MODEL * D_MODEL;       // 1M
    short* xb  = (short*)d_ws;
    short* wqb = xb + nx;
    short* wkb = wqb + nw;
    short* wvb = wkb + nw;
    short* wob = wvb + nw;
    short* Qb  = wob + nw;
    short* Kb  = Qb + nx;
    short* Vt  = Kb + nx;
    short* Ab  = Vt + nx;
    float* costab = (float*)(Ab + nx);
    float* sintab = costab + SEQ * 32;

    dim3 blk(256);
    cvt_bf16_kernel<<<dim3(4352), blk, 0, stream>>>(x, wq, wk, wv, wo, pos,
                                                    xb, wqb, wkb, wvb, wob,
                                                    costab, sintab);
    qkv_mfma_kernel<<<dim3(768), blk, 0, stream>>>(xb, wqb, wkb, wvb,
                                                   costab, sintab, Qb, Kb, Vt);
    attn_mfma_kernel<<<dim3(BATCH * NUM_HEADS * (SEQ / 64)), blk, 0, stream>>>(Qb, Kb, Vt, Ab);
    out_mfma_kernel<<<dim3(256), blk, 0, stream>>>(Ab, wob, out);
}